// Round 7
// baseline (231.801 us; speedup 1.0000x reference)
//
#include <hip/hip_runtime.h>
#include <hip/hip_bf16.h>

// Problem: B=8, N=4096, H=256, F=6
//   Wt[b][n][h] = sum_f osc[f][h][n] * sin(freq_f * t[b] + phase[f][n])
//   out[b][m][n] = sum_h x[b][m][h] * Wt[b][n][h]
//
// R15 = R13 (91.57, best) fused into ONE ORDINARY launch with a per-b
//       producer-counter barrier (no cooperative API — R14 showed
//       hipLaunchCooperativeKernel doesn't work under graph capture).
//   - Block (mTile,b) builds slice (h0=(mTile&15)*16, n0=((mTile>>4)&3)*64)
//     of Wt[b]: the 64 builders of Wt[b] ARE the 64 gemm blocks of b ->
//     self-contained contiguous cohort, deadlock-free (grid 512 = exact
//     2-blocks/CU capacity anyway).
//   - Release: __threadfence + __syncthreads + tid0 release-atomicAdd.
//     Consume: per-wave relaxed spin until cnt[b]==64, then agent-acquire
//     fence (invalidates local caches -> no stale cross-XCD poison).
//   - cnt at d_ws+2MB (64B-padded per b), zeroed via stream-ordered
//     hipMemsetAsync (capture-legal; harness uses it itself).
//   - Gemm phase: R13 verbatim. A(0) prefetched BEFORE the spin.

#define B_  8
#define N_  4096
#define H_  256

typedef __attribute__((ext_vector_type(8))) short s8v;   // 8 bf16 (A/B frag)
typedef __attribute__((ext_vector_type(4))) float f4v;   // C/D frag / 16B store

#define AS1 __attribute__((address_space(1)))
#define AS3 __attribute__((address_space(3)))
#define GLOAD_LDS16(g, l) \
    __builtin_amdgcn_global_load_lds((const AS1 void*)(g), (AS3 void*)(l), 16, 0, 0)

#define LDA 72    // As row stride in shorts (144 B, 2-way class, clean — R6)

__global__ __launch_bounds__(512, 4) void fused(
    const float* __restrict__ X,              // [8][4096][256] fp32
    const float* __restrict__ t,              // [8][1]
    const float* __restrict__ osc,            // [6][256][256]  osc[f][h][n]
    const float* __restrict__ phase,          // [6][256]       phase[f][n]
    __hip_bfloat16* Wt,                       // ws: [8][256][256] bf16
    unsigned int* cnt,                        // ws+2MB: [8] x 16 uints (64B pad)
    float* __restrict__ out)                  // [8][4096][256] fp32
{
    __shared__ float tr[16 * 68];             //  4.4 KB (build transpose)
    __shared__ short As[64 * LDA];            //  9.2 KB
    __shared__ short Bs[2][256 * 64];         // 64.0 KB  -> 77.7 KB total, 2/CU

    const int tid = threadIdx.x;
    const int b     = blockIdx.y;             // 0..7
    const int mTile = blockIdx.x;             // 0..63

    // ================= phase 1: build own slice of Wt[b] ================
    {
        const int h0 = (mTile & 15) * 16;     // 16 h-slices
        const int n0 = ((mTile >> 4) & 3) * 64;  // 4 n-tiles
        if (tid < 256) {
            const float freqs[6] = {1.f, 2.f, 4.f, 8.f, 7.f, 5.f};
            const float tb = t[b];
            const int nr = (tid & 15) * 4;
            const int hr = tid >> 4;          // 0..15
            float s[6][4];
#pragma unroll
            for (int f = 0; f < 6; ++f)
#pragma unroll
                for (int j = 0; j < 4; ++j)
                    s[f][j] = __sinf(freqs[f] * tb + phase[f * 256 + n0 + nr + j]);

            const int h = h0 + hr;
            float4 acc = make_float4(0.f, 0.f, 0.f, 0.f);
#pragma unroll
            for (int f = 0; f < 6; ++f) {
                float4 o = *(const float4*)&osc[f * 65536 + h * 256 + n0 + nr];
                acc.x += o.x * s[f][0];
                acc.y += o.y * s[f][1];
                acc.z += o.z * s[f][2];
                acc.w += o.w * s[f][3];
            }
            *(float4*)&tr[hr * 68 + nr] = acc;
        }
        __syncthreads();
        if (tid < 256) {
            const int nw = tid >> 2;          // 0..63
            const int hw = (tid & 3) * 4;     // 0,4,8,12
            float v0 = tr[(hw + 0) * 68 + nw];
            float v1 = tr[(hw + 1) * 68 + nw];
            float v2 = tr[(hw + 2) * 68 + nw];
            float v3 = tr[(hw + 3) * 68 + nw];
            union { __hip_bfloat162 h2[2]; unsigned long long q; } cv;
            cv.h2[0] = __float22bfloat162_rn(make_float2(v0, v1));
            cv.h2[1] = __float22bfloat162_rn(make_float2(v2, v3));
            *(unsigned long long*)(Wt + (size_t)b * 65536 +
                                   (size_t)(n0 + nw) * 256 + h0 + hw) = cv.q;
        }
    }

    // ================= gemm setup (R13 verbatim) + A(0) prefetch ========
    const int lane   = tid & 63;
    const int wave   = tid >> 6;              // 0..7
    const int lane15 = lane & 15;
    const int quad   = lane >> 4;             // 0..3
    const int wm     = wave >> 2;             // 0..1
    const int wn     = wave & 3;              // 0..3

    const float* Xb          = X   + (size_t)b * N_ * H_ + (size_t)mTile * 64 * H_;
    const __hip_bfloat16* Wb = Wt  + (size_t)b * H_ * H_;
    float* Ob                = out + (size_t)b * N_ * H_ + (size_t)mTile * 64 * H_;

    const int arow = tid >> 3;                // 0..63
    const int aseg = (tid & 7) * 8;           // 0,8,..,56
    const float* pa = Xb + (size_t)arow * H_ + aseg;

    const int brow = lane >> 3;               // 0..7
    const int bK   = lane >> 5;               // 0..1
    const __hip_bfloat16* WbRow = Wb + (size_t)(wave * 32 + brow) * H_;

#define ISSUE_B(buf, kt)                                                      \
    do {                                                                      \
        _Pragma("unroll")                                                     \
        for (int j = 0; j < 4; ++j) {                                         \
            const int csrc = (lane & 7) ^ (j * 2 + bK);                       \
            GLOAD_LDS16(WbRow + (size_t)j * 8 * H_ + (kt) * 64 + csrc * 8,    \
                        &Bs[buf][wave * 2048 + j * 512]);                     \
        }                                                                     \
    } while (0)

    // A(0) prefetch before the barrier: X latency hides under build/spin.
    float4 av[2][2];
    av[0][0] = *(const float4*)(pa + 0);
    av[0][1] = *(const float4*)(pa + 4);

    // ---- release: this block's Wt slice is done ----
    __threadfence();                          // device-scope release of slice stores
    __syncthreads();                          // all 512 threads' fences done
    if (tid == 0)
        __hip_atomic_fetch_add(&cnt[b * 16], 1u,
                               __ATOMIC_RELEASE, __HIP_MEMORY_SCOPE_AGENT);

    // ---- acquire: wait for all 64 builders of Wt[b] ----
    if (lane == 0) {
        while (__hip_atomic_load(&cnt[b * 16],
                                 __ATOMIC_RELAXED, __HIP_MEMORY_SCOPE_AGENT) < 64u) {}
    }
    __builtin_amdgcn_fence(__ATOMIC_ACQUIRE, "agent");  // invalidate local caches
    __syncthreads();

    // ================= phase 2: gemm (R13 verbatim) =====================
    f4v acc[2][4] = {};
    ISSUE_B(0, 0);                            // Wt[b] ready

#pragma unroll
    for (int it = 0; it < 4; ++it) {
        const int p = it & 1;
        union { __hip_bfloat162 h2[4]; uint4 q; } cv;
        cv.h2[0] = __float22bfloat162_rn(make_float2(av[p][0].x, av[p][0].y));
        cv.h2[1] = __float22bfloat162_rn(make_float2(av[p][0].z, av[p][0].w));
        cv.h2[2] = __float22bfloat162_rn(make_float2(av[p][1].x, av[p][1].y));
        cv.h2[3] = __float22bfloat162_rn(make_float2(av[p][1].z, av[p][1].w));
        *(uint4*)&As[arow * LDA + aseg] = cv.q;

        if (it < 3) {
            ISSUE_B(p ^ 1, it + 1);
            av[p ^ 1][0] = *(const float4*)(pa + (it + 1) * 64);
            av[p ^ 1][1] = *(const float4*)(pa + (it + 1) * 64 + 4);
            // newest 6 vmem = B(it+1) x4 + A(it+1) x2 -> vmcnt(6) drains B(it)
            asm volatile("s_waitcnt vmcnt(6) lgkmcnt(0)\n\ts_barrier" ::: "memory");
        } else {
            asm volatile("s_waitcnt vmcnt(0) lgkmcnt(0)\n\ts_barrier" ::: "memory");
        }

#pragma unroll
        for (int kh = 0; kh < 2; ++kh) {
            s8v af[2], bf[4];
#pragma unroll
            for (int mt = 0; mt < 2; ++mt)
                af[mt] = *(const s8v*)&As[(wm * 32 + mt * 16 + lane15) * LDA + kh * 32 + quad * 8];
#pragma unroll
            for (int nt = 0; nt < 4; ++nt) {
                const int n  = wn * 64 + lane15 * 4 + nt;
                const int pc = ((kh * 4 + quad) ^ (lane15 & 7)) * 8;  // XOR on read
                bf[nt] = *(const s8v*)&Bs[p][n * 64 + pc];
            }
#pragma unroll
            for (int mt = 0; mt < 2; ++mt)
#pragma unroll
                for (int nt = 0; nt < 4; ++nt)
                    acc[mt][nt] = __builtin_amdgcn_mfma_f32_16x16x32_bf16(
                        af[mt], bf[nt], acc[mt][nt], 0, 0, 0);
        }
        if (it < 3)
            asm volatile("s_barrier" ::: "memory");  // Bs[p] reads retired
    }

    // epilogue: row = wm*32+mt*16+quad*4+r, n = wn*64+lane15*4+nt
    //           -> 4 rows x 256 B contiguous per instr, nontemporal.
#pragma unroll
    for (int mt = 0; mt < 2; ++mt) {
#pragma unroll
        for (int r = 0; r < 4; ++r) {
            const int row = wm * 32 + mt * 16 + quad * 4 + r;
            f4v o = { acc[mt][0][r], acc[mt][1][r], acc[mt][2][r], acc[mt][3][r] };
            __builtin_nontemporal_store(o,
                (f4v*)(Ob + (size_t)row * H_ + wn * 64 + lane15 * 4));
        }
    }
}

extern "C" void kernel_launch(void* const* d_in, const int* in_sizes, int n_in,
                              void* d_out, int out_size, void* d_ws, size_t ws_size,
                              hipStream_t stream) {
    const float* x     = (const float*)d_in[0];   // [8][4096][256]
    const float* t     = (const float*)d_in[1];   // [8][1]
    const float* osc   = (const float*)d_in[2];   // [6][256][256]
    const float* phase = (const float*)d_in[3];   // [6][256]
    __hip_bfloat16* Wt = (__hip_bfloat16*)d_ws;   // first 1 MB of ws
    unsigned int* cnt  = (unsigned int*)((char*)d_ws + (2u << 20));  // ws+2MB
    float* out = (float*)d_out;
    (void)in_sizes; (void)n_in; (void)out_size; (void)ws_size;

    // zero the 8 per-b counters (64 B apart); stream-ordered, capture-legal
    hipMemsetAsync(cnt, 0, 8 * 16 * sizeof(unsigned int), stream);

    fused<<<dim3(64, 8), 512, 0, stream>>>(x, t, osc, phase, Wt, cnt, out);
}

// Round 8
// 93.436 us; speedup vs baseline: 2.4808x; 2.4808x over previous
//
#include <hip/hip_runtime.h>
#include <hip/hip_bf16.h>

// Problem: B=8, N=4096, H=256, F=6
//   Wt[b][n][h] = sum_f osc[f][h][n] * sin(freq_f * t[b] + phase[f][n])
//   out[b][m][n] = sum_h x[b][m][h] * Wt[b][n][h]
//
// R16 = R13 (91.57, best) with gemm re-tiled BM=64 x BN=128 for occupancy.
//   Fusion abandoned: R14 (coop launch) fails under graph capture; R15
//   (atomic producer barrier) passed but cost 180 µs in fence/spin
//   machinery — the kernel boundary does cross-XCD release/acquire for
//   free. Two launches stay.
//   gemm change: 1024 blocks (64 mTiles x 2 nTiles x 8 b), LDS 41.2 KB
//   (As 9.2 + Bs 2x16 KB) -> 3 blocks/CU (launch_bounds(512,6)) and
//   ~1.33 residency rounds: prologue/epilogue latency bubbles of one
//   block overlap other blocks' compute (R13 ran exactly 1 lockstep
//   round at 2/CU with nothing to overlap). X re-read by an mTile's two
//   nTile blocks is same-XCD (id delta 64 = 0 mod 8) -> L2-absorbed.
//   Swizzle re-derived for 128-row panels: source key (row>>2)&7 =
//   (wave&1)*4 + j*2 + (lane>>5); read pc = ((kh*4+quad)^(lane15&7))
//   unchanged. A path / numerics order identical to R13.

#define B_  8
#define N_  4096
#define H_  256

typedef __attribute__((ext_vector_type(8))) short s8v;   // 8 bf16 (A/B frag)
typedef __attribute__((ext_vector_type(4))) float f4v;   // C/D frag / 16B store

#define AS1 __attribute__((address_space(1)))
#define AS3 __attribute__((address_space(3)))
#define GLOAD_LDS16(g, l) \
    __builtin_amdgcn_global_load_lds((const AS1 void*)(g), (AS3 void*)(l), 16, 0, 0)

__global__ __launch_bounds__(256) void build_w(
    const float* __restrict__ osc,     // [6][256][256]  osc[f][h][n]
    const float* __restrict__ t,       // [8][1]
    const float* __restrict__ phase,   // [6][256]       phase[f][n]
    __hip_bfloat16* __restrict__ Wt)   // [8][256][256]  Wt[b][n][h]
{
    const float freqs[6] = {1.f, 2.f, 4.f, 8.f, 7.f, 5.f};
    __shared__ float tr[16 * 68];      // [hlocal][n], stride 68

    const int b  = blockIdx.z;
    const int n0 = blockIdx.y * 64;    // 4 n-tiles
    const int h0 = blockIdx.x * 16;    // 16 h-slices
    const int tid = threadIdx.x;

    const float tb = t[b];
    const int nr = (tid & 15) * 4;
    const int hr = tid >> 4;           // 0..15
    float s[6][4];
#pragma unroll
    for (int f = 0; f < 6; ++f)
#pragma unroll
        for (int j = 0; j < 4; ++j)
            s[f][j] = __sinf(freqs[f] * tb + phase[f * 256 + n0 + nr + j]);

    const int h = h0 + hr;
    float4 acc = make_float4(0.f, 0.f, 0.f, 0.f);
#pragma unroll
    for (int f = 0; f < 6; ++f) {
        float4 o = *(const float4*)&osc[f * 65536 + h * 256 + n0 + nr];
        acc.x += o.x * s[f][0];
        acc.y += o.y * s[f][1];
        acc.z += o.z * s[f][2];
        acc.w += o.w * s[f][3];
    }
    *(float4*)&tr[hr * 68 + nr] = acc;
    __syncthreads();

    const int nw = tid >> 2;           // 0..63
    const int hw = (tid & 3) * 4;      // 0,4,8,12
    float v0 = tr[(hw + 0) * 68 + nw];
    float v1 = tr[(hw + 1) * 68 + nw];
    float v2 = tr[(hw + 2) * 68 + nw];
    float v3 = tr[(hw + 3) * 68 + nw];
    union { __hip_bfloat162 h2[2]; unsigned long long q; } cv;
    cv.h2[0] = __float22bfloat162_rn(make_float2(v0, v1));
    cv.h2[1] = __float22bfloat162_rn(make_float2(v2, v3));
    *(unsigned long long*)(Wt + (size_t)b * 65536 + (size_t)(n0 + nw) * 256 + h0 + hw) = cv.q;
}

#define LDA 72    // As row stride in shorts (144 B, 2-way class, clean — R6)

// BM=64, BN=128, BK=64 x 4 iters. 8 waves: wm=wave>>1 (16-row band),
// wn=wave&1 (64-col band). 1024 blocks, 3 blocks/CU.
__global__ __launch_bounds__(512, 6) void gemm(
    const float* __restrict__ X,              // [8][4096][256] fp32
    const __hip_bfloat16* __restrict__ Wt,    // [8][256][256]  bf16 [b][n][h]
    float* __restrict__ out)                  // [8][4096][256] fp32
{
    __shared__ short As[64 * LDA];            //  9.2 KB, reg-staged (fp32->bf16)
    __shared__ short Bs[2][128 * 64];         // 2x16 KB dense, XOR-swizzled content
                                              // total 41.2 KB -> 3 blocks/CU

    const int b     = blockIdx.z;             // 0..7
    const int nTile = blockIdx.y;             // 0..1
    const int mTile = blockIdx.x;             // 0..63

    const int tid    = threadIdx.x;
    const int lane   = tid & 63;
    const int wave   = tid >> 6;              // 0..7
    const int lane15 = lane & 15;
    const int quad   = lane >> 4;             // 0..3
    const int wm     = wave >> 1;             // 0..3: 16-row band
    const int wn     = wave & 1;              // 0..1: 64-col band

    const float* Xb          = X   + (size_t)b * N_ * H_ + (size_t)mTile * 64 * H_;
    const __hip_bfloat16* Wb = Wt  + (size_t)b * H_ * H_ + (size_t)nTile * 128 * H_;
    float* Ob                = out + (size_t)b * N_ * H_ + (size_t)mTile * 64 * H_
                                   + (size_t)nTile * 128;

    // A staging: 64 rows x 64 k fp32 -> 8 floats/thread (32 B contig)
    const int arow = tid >> 3;                // 0..63
    const int aseg = (tid & 7) * 8;           // 0,8,..,56
    const float* pa = Xb + (size_t)arow * H_ + aseg;

    // B gload_lds: LINEAR LDS dest; 2 chunks/thread.
    //   chunk d = wave*128 + j*64 + lane -> row = wave*16 + j*8 + (lane>>3),
    //   c_phys = lane&7. Source reads logical chunk c_phys ^ ((row>>2)&7),
    //   (row>>2)&7 = (wave&1)*4 + j*2 + (lane>>5).
    const int brow = lane >> 3;               // 0..7
    const int bK   = lane >> 5;               // 0..1
    const __hip_bfloat16* WbRow = Wb + (size_t)(wave * 16 + brow) * H_;

#define ISSUE_B(buf, kt)                                                      \
    do {                                                                      \
        _Pragma("unroll")                                                     \
        for (int j = 0; j < 2; ++j) {                                         \
            const int csrc = (lane & 7) ^ ((wave & 1) * 4 + j * 2 + bK);      \
            GLOAD_LDS16(WbRow + (size_t)j * 8 * H_ + (kt) * 64 + csrc * 8,    \
                        &Bs[buf][wave * 1024 + j * 512 + 0]);                 \
        }                                                                     \
    } while (0)

    f4v acc[4] = {};

    // ---- prologue: B(0) -> Bs[0], A(0) -> regs
    ISSUE_B(0, 0);
    float4 av[2][2];
    av[0][0] = *(const float4*)(pa + 0);
    av[0][1] = *(const float4*)(pa + 4);

#pragma unroll
    for (int it = 0; it < 4; ++it) {
        const int p = it & 1;
        // stage A(it): fp32 -> bf16 in-register, one ds_write_b128
        union { __hip_bfloat162 h2[4]; uint4 q; } cv;
        cv.h2[0] = __float22bfloat162_rn(make_float2(av[p][0].x, av[p][0].y));
        cv.h2[1] = __float22bfloat162_rn(make_float2(av[p][0].z, av[p][0].w));
        cv.h2[2] = __float22bfloat162_rn(make_float2(av[p][1].x, av[p][1].y));
        cv.h2[3] = __float22bfloat162_rn(make_float2(av[p][1].z, av[p][1].w));
        *(uint4*)&As[arow * LDA + aseg] = cv.q;

        if (it < 3) {
            // issue B(it+1) (2 loads) and A(it+1) (2 loads); counted vmcnt
            // keeps them in flight across the barrier, drains B(it).
            ISSUE_B(p ^ 1, it + 1);
            av[p ^ 1][0] = *(const float4*)(pa + (it + 1) * 64);
            av[p ^ 1][1] = *(const float4*)(pa + (it + 1) * 64 + 4);
            asm volatile("s_waitcnt vmcnt(4) lgkmcnt(0)\n\ts_barrier" ::: "memory");
        } else {
            asm volatile("s_waitcnt vmcnt(0) lgkmcnt(0)\n\ts_barrier" ::: "memory");
        }

        // compute on As + Bs[p]; col lane15 <- B row n = wn*64+lane15*4+nt
#pragma unroll
        for (int kh = 0; kh < 2; ++kh) {
            s8v af, bf[4];
            af = *(const s8v*)&As[(wm * 16 + lane15) * LDA + kh * 32 + quad * 8];
#pragma unroll
            for (int nt = 0; nt < 4; ++nt) {
                const int n  = wn * 64 + lane15 * 4 + nt;       // 0..127
                // logical chunk kh*4+quad; key (n>>2)&7 = lane15&7
                const int pc = ((kh * 4 + quad) ^ (lane15 & 7)) * 8;
                bf[nt] = *(const s8v*)&Bs[p][n * 64 + pc];
            }
#pragma unroll
            for (int nt = 0; nt < 4; ++nt)
                acc[nt] = __builtin_amdgcn_mfma_f32_16x16x32_bf16(
                    af, bf[nt], acc[nt], 0, 0, 0);
        }
        if (it < 3)
            asm volatile("s_barrier" ::: "memory");  // Bs[p] reads retired
    }

    // epilogue: acc[nt][r] holds (row = wm*16+quad*4+r, n = wn*64+lane15*4+nt)
    //           -> 16 B contiguous per lane, 4 rows x 256 B per instr.
#pragma unroll
    for (int r = 0; r < 4; ++r) {
        const int row = wm * 16 + quad * 4 + r;
        f4v o = { acc[0][r], acc[1][r], acc[2][r], acc[3][r] };
        __builtin_nontemporal_store(o,
            (f4v*)(Ob + (size_t)row * H_ + wn * 64 + lane15 * 4));
    }
}

extern "C" void kernel_launch(void* const* d_in, const int* in_sizes, int n_in,
                              void* d_out, int out_size, void* d_ws, size_t ws_size,
                              hipStream_t stream) {
    const float* x     = (const float*)d_in[0];   // [8][4096][256]
    const float* t     = (const float*)d_in[1];   // [8][1]
    const float* osc   = (const float*)d_in[2];   // [6][256][256]
    const float* phase = (const float*)d_in[3];   // [6][256]
    __hip_bfloat16* Wt = (__hip_bfloat16*)d_ws;   // ws poison is unconditional -> free
    float* out = (float*)d_out;
    (void)in_sizes; (void)n_in; (void)out_size; (void)ws_size;

    dim3 gw(16, 4, 8);                            // (h-slice, n-tile, b) = 512 blocks
    build_w<<<gw, 256, 0, stream>>>(osc, t, phase, Wt);

    dim3 gg(64, 2, 8);                            // (mTile, nTile, b) = 1024 blocks
    gemm<<<gg, 512, 0, stream>>>(x, Wt, out);
}